// Round 4
// baseline (1700.834 us; speedup 1.0000x reference)
//
#include <hip/hip_runtime.h>
#include <math.h>

// ---------------------------------------------------------------------------
// ConvexGenerator. Round 4: latency-bound MFMA loops -> pipelined K-loops.
// R3 rocprof: k_logits_mfma 191us with MfmaUtil 2.8 / VALU 1.6 / HBM 5.5% --
// all pipes idle; kernel ran at exactly its un-overlapped request rate.
// Fixes: (1) 256-row M-tiles so Wf/Xf are read once per class (halves B-op
// traffic), (2) 4x4 frag acc per wave (16 MFMA/K-step), (3) distance-2
// software pipeline: global loads for step k+2 issued before step k's MFMAs,
// LDS A-tile double-buffered, one barrier per step.
// Frag layouts (HW-verified): A[m=lane&15][k=(lane>>4)*8+j],
// B[k=(lane>>4)*8+j][n=lane&15], C/D col=lane&15 row=(lane>>4)*4+reg.
// ---------------------------------------------------------------------------

constexpr int B = 2048, LATENT = 128, C = 8, HID = 1024, D = 512, NMAX = 4096;

typedef __attribute__((ext_vector_type(8))) short bf16x8;
typedef __attribute__((ext_vector_type(4))) float f32x4;

__device__ __forceinline__ int class_count(int c) {
    if (c < 6) return 1024 + 512 * c;
    return (c == 6) ? 3840 : 4096;
}

__device__ __forceinline__ float gelu_exact(float x) {
    return 0.5f * x * (1.0f + erff(x * 0.70710678118654752f));
}

__device__ __forceinline__ unsigned short f2bf(float f) {  // RNE
    unsigned int u = __float_as_uint(f);
    return (unsigned short)((u + 0x7fffu + ((u >> 16) & 1u)) >> 16);
}

__device__ __forceinline__ float waveMax(float v) {
    #pragma unroll
    for (int o = 32; o > 0; o >>= 1) v = fmaxf(v, __shfl_down(v, o));
    return v;
}
__device__ __forceinline__ float waveSum(float v) {
    #pragma unroll
    for (int o = 32; o > 0; o >>= 1) v += __shfl_down(v, o);
    return v;
}

// --- per-class gather lists (order-independent -> atomics replay-safe) ------
__global__ void k_gather(const int* __restrict__ cid, int* __restrict__ cnt,
                         int* __restrict__ idx) {
    int b = blockIdx.x * 256 + threadIdx.x;
    if (b < B) {
        int c = cid[b];
        int s = atomicAdd(&cnt[c], 1);
        idx[c * B + s] = b;
    }
}

// --- fp32 -> bf16 bulk convert (for z) --------------------------------------
__global__ void k_f2bf(const float* __restrict__ src,
                       unsigned short* __restrict__ dst, int n4) {
    int i = blockIdx.x * 256 + threadIdx.x;
    if (i < n4) {
        float4 v = *(const float4*)&src[(size_t)i * 4];
        ushort4 o = {f2bf(v.x), f2bf(v.y), f2bf(v.z), f2bf(v.w)};
        *(ushort4*)&dst[(size_t)i * 4] = o;
    }
}

// --- repack: src [R][Cc] fp32 -> bf16 MFMA B-frags --------------------------
// frag (ctile, rblk): lane=(q*16+n), elem j = src[rblk*32+q*8+j][ctile*16+n];
// frag index = (ctile*(R/32)+rblk)*512.
__global__ __launch_bounds__(256) void k_repack_frag(
    const float* __restrict__ src, unsigned short* __restrict__ dst,
    int R, int Cc, size_t srcStride, size_t dstStride, int limitMode) {
    const int cls = blockIdx.z;
    const int rb = blockIdx.x;
    const int c0 = blockIdx.y * 256;
    if (limitMode == 1 && c0 >= class_count(cls)) return;
    if (limitMode == 2 && rb * 32 >= class_count(cls)) return;
    src += (size_t)cls * srcStride;
    dst += (size_t)cls * dstStride;
    __shared__ float T[32][257];
    const int t = threadIdx.x;
    #pragma unroll
    for (int i = 0; i < 8; ++i) {
        int r = i * 4 + (t >> 6);
        int cc = (t & 63) * 4;
        float4 v = *(const float4*)&src[(size_t)(rb * 32 + r) * Cc + c0 + cc];
        T[r][cc] = v.x; T[r][cc + 1] = v.y; T[r][cc + 2] = v.z; T[r][cc + 3] = v.w;
    }
    __syncthreads();
    const int RB = R >> 5;
    #pragma unroll
    for (int i = 0; i < 4; ++i) {
        int ct = i * 4 + (t >> 6);
        int lane = t & 63;
        int n = lane & 15, q = lane >> 4;
        unsigned short tmp[8];
        #pragma unroll
        for (int j = 0; j < 8; ++j) tmp[j] = f2bf(T[q * 8 + j][ct * 16 + n]);
        *(uint4*)&dst[(((size_t)(c0 / 16 + ct)) * RB + rb) * 512 + lane * 8] =
            *(const uint4*)tmp;
    }
}

// ====================== pipelined MFMA GEMM cores ===========================
// Shared shape: 256 threads, 256-row M-tile, 64-col N-tile, BK=32.
// Wave w owns rows [w*64, w*64+64): 4 m-frags x 4 n-frags = 64 VGPR acc.
// Thread t stages rows (t>>2)+j*64 (j<4), k-chunk (t&3)*8.

#define PIPE_LOOP(KBv, A_ADDR, B_ADDR)                                        \
    uint4 aload[4]; bf16x8 bcur[4], bnxt[4];                                  \
    _Pragma("unroll") for (int j = 0; j < 4; ++j)                             \
        aload[j] = *(const uint4*)A_ADDR(j, 0);                               \
    _Pragma("unroll") for (int f = 0; f < 4; ++f)                             \
        bcur[f] = *(const bf16x8*)B_ADDR(f, 0);                               \
    _Pragma("unroll") for (int j = 0; j < 4; ++j)                             \
        *(uint4*)&As[0][((t >> 2) + j * 64) * 40 + rch * 8] = aload[j];       \
    _Pragma("unroll") for (int j = 0; j < 4; ++j)                             \
        aload[j] = *(const uint4*)A_ADDR(j, 1);                               \
    _Pragma("unroll") for (int f = 0; f < 4; ++f)                             \
        bnxt[f] = *(const bf16x8*)B_ADDR(f, 1);                               \
    __syncthreads();                                                          \
    for (int kb = 0; kb < KBv; ++kb) {                                        \
        uint4 anew[4]; bf16x8 bnew[4];                                        \
        if (kb + 2 < KBv) {                                                   \
            _Pragma("unroll") for (int j = 0; j < 4; ++j)                     \
                anew[j] = *(const uint4*)A_ADDR(j, kb + 2);                   \
            _Pragma("unroll") for (int f = 0; f < 4; ++f)                     \
                bnew[f] = *(const bf16x8*)B_ADDR(f, kb + 2);                  \
        }                                                                     \
        _Pragma("unroll") for (int mt = 0; mt < 4; ++mt) {                    \
            bf16x8 af = *(const bf16x8*)&As[kb & 1]                           \
                [(wave * 64 + mt * 16 + ln) * 40 + lq * 8];                   \
            _Pragma("unroll") for (int f = 0; f < 4; ++f)                     \
                acc[mt][f] = __builtin_amdgcn_mfma_f32_16x16x32_bf16(         \
                    af, bcur[f], acc[mt][f], 0, 0, 0);                        \
        }                                                                     \
        if (kb + 1 < KBv) {                                                   \
            _Pragma("unroll") for (int j = 0; j < 4; ++j)                     \
                *(uint4*)&As[(kb + 1) & 1]                                    \
                    [((t >> 2) + j * 64) * 40 + rch * 8] = aload[j];          \
        }                                                                     \
        _Pragma("unroll") for (int f = 0; f < 4; ++f) bcur[f] = bnxt[f];      \
        _Pragma("unroll") for (int f = 0; f < 4; ++f) bnxt[f] = bnew[f];      \
        _Pragma("unroll") for (int j = 0; j < 4; ++j) aload[j] = anew[j];     \
        __syncthreads();                                                      \
    }

// --- MLP layer (dense rows): Out = gelu(A @ W + bias (+ onehot)) bf16 -------
__global__ __launch_bounds__(256, 2) void k_mlp_mfma(
    const unsigned short* __restrict__ A, const unsigned short* __restrict__ Bf,
    const float* __restrict__ bias, const float* __restrict__ Woh,
    const int* __restrict__ cid, unsigned short* __restrict__ Out, int K) {
    const int row0 = blockIdx.x * 256, col0 = blockIdx.y * 64;
    const int KB = K >> 5;
    const int t = threadIdx.x, wave = t >> 6, lane = t & 63;
    const int ln = lane & 15, lq = lane >> 4;
    const int rch = t & 3;
    __shared__ __align__(16) unsigned short As[2][256 * 40];
    f32x4 acc[4][4] = {};
#define MLP_A(j, kb) &A[(size_t)(row0 + (t >> 2) + (j) * 64) * K + (kb) * 32 + rch * 8]
#define MLP_B(f, kb) &Bf[(((size_t)(col0 >> 4) + (f)) * KB + (kb)) * 512 + lane * 8]
    PIPE_LOOP(KB, MLP_A, MLP_B)
#undef MLP_A
#undef MLP_B
    #pragma unroll
    for (int mt = 0; mt < 4; ++mt) {
        #pragma unroll
        for (int reg = 0; reg < 4; ++reg) {
            int r = row0 + wave * 64 + mt * 16 + lq * 4 + reg;
            const float* woh = Woh ? &Woh[(size_t)cid[r] * HID] : nullptr;
            #pragma unroll
            for (int f = 0; f < 4; ++f) {
                int col = col0 + f * 16 + ln;
                float v = acc[mt][f][reg] + bias[col];
                if (woh) v += woh[col];
                Out[(size_t)r * HID + col] = f2bf(gelu_exact(v));
            }
        }
    }
}

// --- grouped logits GEMM: L[g, n0..n0+63] = t[g] @ Wa[c] + ba ---------------
__global__ __launch_bounds__(256, 2) void k_logits_mfma(
    const unsigned short* __restrict__ T, const unsigned short* __restrict__ Wf,
    const float* __restrict__ ba, const int* __restrict__ cnt,
    const int* __restrict__ idxs, float* __restrict__ L) {
    const int c = blockIdx.y;
    const int count = class_count(c);
    const int n0 = blockIdx.z * 64;
    if (n0 >= count) return;
    const int Mc = cnt[c];
    const int row0 = blockIdx.x * 256;
    if (row0 >= Mc) return;
    const int* idxc = idxs + c * B;
    const unsigned short* Wfc = Wf + (size_t)c * 4194304;
    const int t = threadIdx.x, wave = t >> 6, lane = t & 63;
    const int ln = lane & 15, lq = lane >> 4;
    const int rch = t & 3;
    int gg[4];
    #pragma unroll
    for (int j = 0; j < 4; ++j)
        gg[j] = idxc[min(row0 + (t >> 2) + j * 64, Mc - 1)];
    __shared__ __align__(16) unsigned short As[2][256 * 40];
    f32x4 acc[4][4] = {};
#define LG_A(j, kb) &T[(size_t)gg[j] * HID + (kb) * 32 + rch * 8]
#define LG_B(f, kb) &Wfc[(((size_t)(n0 >> 4) + (f)) * 32 + (kb)) * 512 + lane * 8]
    PIPE_LOOP(32, LG_A, LG_B)
#undef LG_A
#undef LG_B
    #pragma unroll
    for (int mt = 0; mt < 4; ++mt) {
        #pragma unroll
        for (int reg = 0; reg < 4; ++reg) {
            int r = row0 + wave * 64 + mt * 16 + lq * 4 + reg;
            if (r < Mc) {
                int g = idxc[r];
                #pragma unroll
                for (int f = 0; f < 4; ++f) {
                    int col = n0 + f * 16 + ln;
                    L[(size_t)g * NMAX + col] = acc[mt][f][reg] + ba[c * NMAX + col];
                }
            }
        }
    }
}

// --- softmax over first count cols; writes bf16 alpha -----------------------
__global__ __launch_bounds__(256) void k_softmax(const float* __restrict__ L,
                                                 unsigned short* __restrict__ Aout,
                                                 const int* __restrict__ cid) {
    const int b = blockIdx.x;
    const int n = class_count(cid[b]);
    const float* row = L + (size_t)b * NMAX;
    unsigned short* orow = Aout + (size_t)b * NMAX;
    const int t = threadIdx.x;
    float v[16];
    int nv = 0;
    float mx = -INFINITY;
    for (int i = t; i < n; i += 256) {
        float x = row[i];
        v[nv++] = x;
        mx = fmaxf(mx, x);
    }
    __shared__ float red[4], red2[4];
    float wm = waveMax(mx);
    int wid = t >> 6, lid = t & 63;
    if (lid == 0) red[wid] = wm;
    __syncthreads();
    float bmax = fmaxf(fmaxf(red[0], red[1]), fmaxf(red[2], red[3]));
    float s = 0.f;
    #pragma unroll
    for (int j = 0; j < 16; ++j)
        if (j < nv) { v[j] = expf(v[j] - bmax); s += v[j]; }
    float ws_ = waveSum(s);
    if (lid == 0) red2[wid] = ws_;
    __syncthreads();
    float inv = 1.0f / (red2[0] + red2[1] + red2[2] + red2[3]);
    int j = 0;
    for (int i = t; i < n; i += 256) orow[i] = f2bf(v[j++] * inv);
}

// --- grouped synth GEMM, split-K(1024) + atomicAdd --------------------------
// blockIdx.z = dtile*4 + kchunk; dtile covers 64 of D, kchunk 1024 of n.
__global__ __launch_bounds__(256, 2) void k_synth_mfma(
    const unsigned short* __restrict__ Al, const unsigned short* __restrict__ Xf,
    const int* __restrict__ cnt, const int* __restrict__ idxs,
    float* __restrict__ Out) {
    const int c = blockIdx.y;
    const int count = class_count(c);
    const int dtile = blockIdx.z >> 2, kci = blockIdx.z & 3;
    const int kc0 = kci * 1024;
    if (kc0 >= count) return;
    const int KB = (min(kc0 + 1024, count) - kc0) >> 5;   // 8..32
    const int Mc = cnt[c];
    const int row0 = blockIdx.x * 256;
    if (row0 >= Mc) return;
    const int* idxc = idxs + c * B;
    const unsigned short* Xfc = Xf + (size_t)c * 2097152;
    const int d0 = dtile * 64, kbg0 = kc0 >> 5;
    const int t = threadIdx.x, wave = t >> 6, lane = t & 63;
    const int ln = lane & 15, lq = lane >> 4;
    const int rch = t & 3;
    int gg[4];
    #pragma unroll
    for (int j = 0; j < 4; ++j)
        gg[j] = idxc[min(row0 + (t >> 2) + j * 64, Mc - 1)];
    __shared__ __align__(16) unsigned short As[2][256 * 40];
    f32x4 acc[4][4] = {};
#define SY_A(j, kb) &Al[(size_t)gg[j] * NMAX + kc0 + (kb) * 32 + rch * 8]
#define SY_B(f, kb) &Xfc[(((size_t)(d0 >> 4) + (f)) * 128 + kbg0 + (kb)) * 512 + lane * 8]
    PIPE_LOOP(KB, SY_A, SY_B)
#undef SY_A
#undef SY_B
    #pragma unroll
    for (int mt = 0; mt < 4; ++mt) {
        #pragma unroll
        for (int reg = 0; reg < 4; ++reg) {
            int r = row0 + wave * 64 + mt * 16 + lq * 4 + reg;
            if (r < Mc) {
                int g = idxc[r];
                #pragma unroll
                for (int f = 0; f < 4; ++f)
                    atomicAdd(&Out[(size_t)g * D + d0 + f * 16 + ln], acc[mt][f][reg]);
            }
        }
    }
}

// ---------------------------------------------------------------------------
extern "C" void kernel_launch(void* const* d_in, const int* in_sizes, int n_in,
                              void* d_out, int out_size, void* d_ws,
                              size_t ws_size, hipStream_t stream) {
    const float* z    = (const float*)d_in[0];
    const int*   cid  = (const int*)d_in[1];
    const float* W1   = (const float*)d_in[2];
    const float* b1   = (const float*)d_in[3];
    const float* W2   = (const float*)d_in[4];
    const float* b2   = (const float*)d_in[5];
    const float* Wa   = (const float*)d_in[6];
    const float* ba   = (const float*)d_in[7];
    const float* Xbuf = (const float*)d_in[8];
    float* out = (float*)d_out;

    char* ws = (char*)d_ws;
    int*            cnt   = (int*)ws;                           // 256
    int*            idx   = (int*)(ws + 256);                   // 64 KB
    unsigned short* zbf   = (unsigned short*)(ws + 65792);      // 512 KB
    unsigned short* h     = (unsigned short*)(ws + 590080);     // 4 MB
    unsigned short* tbuf  = (unsigned short*)(ws + 4784384);    // 4 MB
    float*          L     = (float*)(ws + 8978688);             // 32 MB
    unsigned short* abuf  = (unsigned short*)(ws + 42533120);   // 16 MB
    unsigned short* Wf    = (unsigned short*)(ws + 59310336);   // 64 MB
    unsigned short* Xf    = (unsigned short*)(ws + 126419200);  // 32 MB
    unsigned short* W2f   = (unsigned short*)(ws + 159973632);  // 2 MB
    unsigned short* W1f   = (unsigned short*)(ws + 162070784);  // 256 KB

    hipMemsetAsync(cnt, 0, 256, stream);
    k_gather<<<dim3(B / 256), 256, 0, stream>>>(cid, cnt, idx);
    k_f2bf<<<dim3(256), 256, 0, stream>>>(z, zbf, B * LATENT / 4);
    k_repack_frag<<<dim3(4, 4, 1), 256, 0, stream>>>(W1, W1f, 128, HID, 0, 0, 0);
    k_repack_frag<<<dim3(32, 4, 1), 256, 0, stream>>>(W2, W2f, HID, HID, 0, 0, 0);
    k_repack_frag<<<dim3(32, 16, C), 256, 0, stream>>>(
        Wa, Wf, HID, NMAX, (size_t)HID * NMAX, 4194304, 1);
    k_repack_frag<<<dim3(128, 2, C), 256, 0, stream>>>(
        Xbuf, Xf, NMAX, D, (size_t)NMAX * D, 2097152, 2);
    k_mlp_mfma<<<dim3(B / 256, HID / 64), 256, 0, stream>>>(
        zbf, W1f, b1, W1 + (size_t)LATENT * HID, cid, h, LATENT);
    k_mlp_mfma<<<dim3(B / 256, HID / 64), 256, 0, stream>>>(
        h, W2f, b2, nullptr, cid, tbuf, HID);
    k_logits_mfma<<<dim3(8, C, NMAX / 64), 256, 0, stream>>>(
        tbuf, Wf, ba, cnt, idx, L);
    k_softmax<<<dim3(B), 256, 0, stream>>>(L, abuf, cid);
    hipMemsetAsync(out, 0, (size_t)B * D * sizeof(float), stream);
    k_synth_mfma<<<dim3(8, C, 32), 256, 0, stream>>>(
        abuf, Xf, cnt, idx, out);
}

// Round 5
// 497.728 us; speedup vs baseline: 3.4172x; 3.4172x over previous
//
#include <hip/hip_runtime.h>
#include <math.h>

// ---------------------------------------------------------------------------
// ConvexGenerator. Round 5: m97-style global_load_lds GEMM core.
// R4 post-mortem: the register-resident distance-2 pipeline spilled to
// scratch (WRITE_SIZE 21.5->105MB, +244KB/block = 2 uint4/thread/iter) under
// __launch_bounds__(256,2) -> 867us. Fix: in-flight data lives in the DMA
// queue, not VGPRs: both A and B staged via __builtin_amdgcn_global_load_lds
// (width 16), single-buffered LDS, 2-barrier K-loop (guide m97, 874TF class).
// A-tile uses XOR chunk swizzle so the wave-uniform dst constraint coexists
// with conflict-free ds_read_b128 (row stride 128B would otherwise be 8-way).
// B-frags (1KB lane-contiguous) DMA straight to LDS, loaded once per block.
// Frag layouts (HW-verified): A[m=lane&15][k=(lane>>4)*8+j],
// B[k=(lane>>4)*8+j][n=lane&15], C/D col=lane&15 row=(lane>>4)*4+reg.
// ---------------------------------------------------------------------------

constexpr int B = 2048, LATENT = 128, C = 8, HID = 1024, D = 512, NMAX = 4096;

typedef __attribute__((ext_vector_type(8))) short bf16x8;
typedef __attribute__((ext_vector_type(4))) float f32x4;

#define GLD16(gsrc, ldst)                                                     \
    __builtin_amdgcn_global_load_lds(                                         \
        (const __attribute__((address_space(1))) unsigned int*)(gsrc),        \
        (__attribute__((address_space(3))) unsigned int*)(ldst), 16, 0, 0)

__device__ __forceinline__ int class_count(int c) {
    if (c < 6) return 1024 + 512 * c;
    return (c == 6) ? 3840 : 4096;
}

__device__ __forceinline__ float gelu_exact(float x) {
    return 0.5f * x * (1.0f + erff(x * 0.70710678118654752f));
}

__device__ __forceinline__ unsigned short f2bf(float f) {  // RNE
    unsigned int u = __float_as_uint(f);
    return (unsigned short)((u + 0x7fffu + ((u >> 16) & 1u)) >> 16);
}

__device__ __forceinline__ float waveMax(float v) {
    #pragma unroll
    for (int o = 32; o > 0; o >>= 1) v = fmaxf(v, __shfl_down(v, o));
    return v;
}
__device__ __forceinline__ float waveSum(float v) {
    #pragma unroll
    for (int o = 32; o > 0; o >>= 1) v += __shfl_down(v, o);
    return v;
}

// --- per-class gather lists (order-independent -> atomics replay-safe) ------
__global__ void k_gather(const int* __restrict__ cid, int* __restrict__ cnt,
                         int* __restrict__ idx) {
    int b = blockIdx.x * 256 + threadIdx.x;
    if (b < B) {
        int c = cid[b];
        int s = atomicAdd(&cnt[c], 1);
        idx[c * B + s] = b;
    }
}

// --- fp32 -> bf16 bulk convert (for z) --------------------------------------
__global__ void k_f2bf(const float* __restrict__ src,
                       unsigned short* __restrict__ dst, int n4) {
    int i = blockIdx.x * 256 + threadIdx.x;
    if (i < n4) {
        float4 v = *(const float4*)&src[(size_t)i * 4];
        ushort4 o = {f2bf(v.x), f2bf(v.y), f2bf(v.z), f2bf(v.w)};
        *(ushort4*)&dst[(size_t)i * 4] = o;
    }
}

// --- repack: src [R][Cc] fp32 -> bf16 MFMA B-frags --------------------------
// frag (ctile, rblk): lane=(q*16+n), elem j = src[rblk*32+q*8+j][ctile*16+n];
// frag index = (ctile*(R/32)+rblk)*512.
__global__ __launch_bounds__(256) void k_repack_frag(
    const float* __restrict__ src, unsigned short* __restrict__ dst,
    int R, int Cc, size_t srcStride, size_t dstStride, int limitMode) {
    const int cls = blockIdx.z;
    const int rb = blockIdx.x;
    const int c0 = blockIdx.y * 256;
    if (limitMode == 1 && c0 >= class_count(cls)) return;
    if (limitMode == 2 && rb * 32 >= class_count(cls)) return;
    src += (size_t)cls * srcStride;
    dst += (size_t)cls * dstStride;
    __shared__ float T[32][257];
    const int t = threadIdx.x;
    #pragma unroll
    for (int i = 0; i < 8; ++i) {
        int r = i * 4 + (t >> 6);
        int cc = (t & 63) * 4;
        float4 v = *(const float4*)&src[(size_t)(rb * 32 + r) * Cc + c0 + cc];
        T[r][cc] = v.x; T[r][cc + 1] = v.y; T[r][cc + 2] = v.z; T[r][cc + 3] = v.w;
    }
    __syncthreads();
    const int RB = R >> 5;
    #pragma unroll
    for (int i = 0; i < 4; ++i) {
        int ct = i * 4 + (t >> 6);
        int lane = t & 63;
        int n = lane & 15, q = lane >> 4;
        unsigned short tmp[8];
        #pragma unroll
        for (int j = 0; j < 8; ++j) tmp[j] = f2bf(T[q * 8 + j][ct * 16 + n]);
        *(uint4*)&dst[(((size_t)(c0 / 16 + ct)) * RB + rb) * 512 + lane * 8] =
            *(const uint4*)tmp;
    }
}

// ====================== global_load_lds GEMM core ===========================
// 256 thr, 128-row M-tile (wave w rows w*32..w*32+31, 2 m-frags), 64-col
// N-tile (4 f-frags), BK=64 (2 kb). LDS: As 128x64sh (row=128B, chunk-
// swizzled), Bs 8 frags x 1KB. Per step: 6 DMA issues/wave, 2 barriers,
// 16 MFMA/wave. No register-resident pipeline state.
//
// Staging: lane l, issue i: tile row r=w*32+i*8+(l>>3), chunk (l&7)^(r&7)
// (r&7=(l>>3)&7), dst=As+w*2048+i*512 (+lane*16 by HW).
// Read: row r chunk c=kb*4+lq at position c^(r&7), r&7=ln&7.
// B: frag fi=w*2+i <-> (kb=fi>>2, f=fi&3); src kb-row = k0/32 + (w>>1).

#define GEMM_CORE_LOOP(KE, APSTEP, BPSTEP)                                    \
    for (int k0 = 0; k0 < (KE); k0 += 64) {                                   \
        _Pragma("unroll") for (int i = 0; i < 4; ++i)                         \
            GLD16(ap[i] + APSTEP, AsW + i * 512);                             \
        _Pragma("unroll") for (int i = 0; i < 2; ++i)                         \
            GLD16(bp[i] + BPSTEP, BsW + i * 512);                             \
        __syncthreads();                                                      \
        _Pragma("unroll") for (int kb = 0; kb < 2; ++kb) {                    \
            bf16x8 bfr[4];                                                    \
            _Pragma("unroll") for (int f = 0; f < 4; ++f)                     \
                bfr[f] = *(const bf16x8*)&Bs[(kb * 4 + f) * 512 + lane * 8];  \
            _Pragma("unroll") for (int mt = 0; mt < 2; ++mt) {                \
                bf16x8 af = *(const bf16x8*)&As[                              \
                    (wave * 32 + mt * 16 + ln) * 64 +                         \
                    (((kb * 4 + lq) ^ (ln & 7)) * 8)];                        \
                _Pragma("unroll") for (int f = 0; f < 4; ++f)                 \
                    acc[mt][f] = __builtin_amdgcn_mfma_f32_16x16x32_bf16(     \
                        af, bfr[f], acc[mt][f], 0, 0, 0);                     \
            }                                                                 \
        }                                                                     \
        __syncthreads();                                                      \
    }

// --- MLP layer (dense rows): Out = gelu(A @ W + bias (+ onehot)) bf16 -------
__global__ __launch_bounds__(256) void k_mlp_mfma(
    const unsigned short* __restrict__ A, const unsigned short* __restrict__ Bf,
    const float* __restrict__ bias, const float* __restrict__ Woh,
    const int* __restrict__ cid, unsigned short* __restrict__ Out, int K) {
    const int row0 = blockIdx.x * 128, col0 = blockIdx.y * 64;
    const int KBtot = K >> 5;
    const int t = threadIdx.x, wave = t >> 6, lane = t & 63;
    const int ln = lane & 15, lq = lane >> 4;
    __shared__ __align__(16) unsigned short As[128 * 64];
    __shared__ __align__(16) unsigned short Bs[8 * 512];
    const int arowl = lane >> 3;
    const int achk = (lane & 7) ^ arowl;
    const unsigned short* ap[4];
    #pragma unroll
    for (int i = 0; i < 4; ++i)
        ap[i] = A + (size_t)(row0 + wave * 32 + i * 8 + arowl) * K + achk * 8;
    const int kbw = wave >> 1;
    const unsigned short* bp[2];
    #pragma unroll
    for (int i = 0; i < 2; ++i) {
        int f = (wave * 2 + i) & 3;
        bp[i] = Bf + ((size_t)((col0 >> 4) + f) * KBtot + kbw) * 512 + lane * 8;
    }
    unsigned short* AsW = &As[wave * 2048];
    unsigned short* BsW = &Bs[(wave * 2) * 512];
    f32x4 acc[2][4] = {};
    GEMM_CORE_LOOP(K, k0, (size_t)(k0 >> 5) * 512)
    #pragma unroll
    for (int mt = 0; mt < 2; ++mt) {
        #pragma unroll
        for (int reg = 0; reg < 4; ++reg) {
            int r = row0 + wave * 32 + mt * 16 + lq * 4 + reg;
            const float* woh = Woh ? &Woh[(size_t)cid[r] * HID] : nullptr;
            #pragma unroll
            for (int f = 0; f < 4; ++f) {
                int col = col0 + f * 16 + ln;
                float v = acc[mt][f][reg] + bias[col];
                if (woh) v += woh[col];
                Out[(size_t)r * HID + col] = f2bf(gelu_exact(v));
            }
        }
    }
}

// --- grouped logits GEMM: L[g, n0..n0+63] = t[g] @ Wa[c] + ba ---------------
__global__ __launch_bounds__(256) void k_logits_mfma(
    const unsigned short* __restrict__ T, const unsigned short* __restrict__ Wf,
    const float* __restrict__ ba, const int* __restrict__ cnt,
    const int* __restrict__ idxs, float* __restrict__ L) {
    const int c = blockIdx.y;
    const int count = class_count(c);
    const int n0 = blockIdx.z * 64;
    if (n0 >= count) return;
    const int Mc = cnt[c];
    const int row0 = blockIdx.x * 128;
    if (row0 >= Mc) return;
    const int* idxc = idxs + c * B;
    const unsigned short* Wfc = Wf + (size_t)c * 4194304;
    const int t = threadIdx.x, wave = t >> 6, lane = t & 63;
    const int ln = lane & 15, lq = lane >> 4;
    __shared__ __align__(16) unsigned short As[128 * 64];
    __shared__ __align__(16) unsigned short Bs[8 * 512];
    const int arowl = lane >> 3;
    const int achk = (lane & 7) ^ arowl;
    const unsigned short* ap[4];
    #pragma unroll
    for (int i = 0; i < 4; ++i) {
        int g = idxc[min(row0 + wave * 32 + i * 8 + arowl, Mc - 1)];
        ap[i] = T + (size_t)g * HID + achk * 8;
    }
    const int kbw = wave >> 1;
    const unsigned short* bp[2];
    #pragma unroll
    for (int i = 0; i < 2; ++i) {
        int f = (wave * 2 + i) & 3;
        bp[i] = Wfc + ((size_t)((n0 >> 4) + f) * 32 + kbw) * 512 + lane * 8;
    }
    unsigned short* AsW = &As[wave * 2048];
    unsigned short* BsW = &Bs[(wave * 2) * 512];
    f32x4 acc[2][4] = {};
    GEMM_CORE_LOOP(HID, k0, (size_t)(k0 >> 5) * 512)
    #pragma unroll
    for (int mt = 0; mt < 2; ++mt) {
        #pragma unroll
        for (int reg = 0; reg < 4; ++reg) {
            int r = row0 + wave * 32 + mt * 16 + lq * 4 + reg;
            if (r < Mc) {
                int g = idxc[r];
                #pragma unroll
                for (int f = 0; f < 4; ++f) {
                    int col = n0 + f * 16 + ln;
                    L[(size_t)g * NMAX + col] = acc[mt][f][reg] + ba[c * NMAX + col];
                }
            }
        }
    }
}

// --- softmax over first count cols; writes bf16 alpha -----------------------
__global__ __launch_bounds__(256) void k_softmax(const float* __restrict__ L,
                                                 unsigned short* __restrict__ Aout,
                                                 const int* __restrict__ cid) {
    const int b = blockIdx.x;
    const int n = class_count(cid[b]);
    const float* row = L + (size_t)b * NMAX;
    unsigned short* orow = Aout + (size_t)b * NMAX;
    const int t = threadIdx.x;
    float v[16];
    int nv = 0;
    float mx = -INFINITY;
    for (int i = t; i < n; i += 256) {
        float x = row[i];
        v[nv++] = x;
        mx = fmaxf(mx, x);
    }
    __shared__ float red[4], red2[4];
    float wm = waveMax(mx);
    int wid = t >> 6, lid = t & 63;
    if (lid == 0) red[wid] = wm;
    __syncthreads();
    float bmax = fmaxf(fmaxf(red[0], red[1]), fmaxf(red[2], red[3]));
    float s = 0.f;
    #pragma unroll
    for (int j = 0; j < 16; ++j)
        if (j < nv) { v[j] = expf(v[j] - bmax); s += v[j]; }
    float ws_ = waveSum(s);
    if (lid == 0) red2[wid] = ws_;
    __syncthreads();
    float inv = 1.0f / (red2[0] + red2[1] + red2[2] + red2[3]);
    int j = 0;
    for (int i = t; i < n; i += 256) orow[i] = f2bf(v[j++] * inv);
}

// --- grouped synth GEMM, split-K(1024) + atomicAdd --------------------------
// blockIdx.z = dtile*4 + kchunk; dtile covers 64 of D, kchunk 1024 of n.
__global__ __launch_bounds__(256) void k_synth_mfma(
    const unsigned short* __restrict__ Al, const unsigned short* __restrict__ Xf,
    const int* __restrict__ cnt, const int* __restrict__ idxs,
    float* __restrict__ Out) {
    const int c = blockIdx.y;
    const int count = class_count(c);
    const int dtile = blockIdx.z >> 2, kci = blockIdx.z & 3;
    const int kc0 = kci * 1024;
    if (kc0 >= count) return;
    const int KE = min(kc0 + 1024, count) - kc0;   // multiple of 64
    const int Mc = cnt[c];
    const int row0 = blockIdx.x * 128;
    if (row0 >= Mc) return;
    const int* idxc = idxs + c * B;
    const unsigned short* Xfc = Xf + (size_t)c * 2097152;
    const int d0 = dtile * 64;
    const int t = threadIdx.x, wave = t >> 6, lane = t & 63;
    const int ln = lane & 15, lq = lane >> 4;
    __shared__ __align__(16) unsigned short As[128 * 64];
    __shared__ __align__(16) unsigned short Bs[8 * 512];
    const int arowl = lane >> 3;
    const int achk = (lane & 7) ^ arowl;
    const unsigned short* ap[4];
    #pragma unroll
    for (int i = 0; i < 4; ++i) {
        int g = idxc[min(row0 + wave * 32 + i * 8 + arowl, Mc - 1)];
        ap[i] = Al + (size_t)g * NMAX + kc0 + achk * 8;
    }
    const int kbw = wave >> 1;
    const unsigned short* bp[2];
    #pragma unroll
    for (int i = 0; i < 2; ++i) {
        int f = (wave * 2 + i) & 3;
        bp[i] = Xfc + ((size_t)((d0 >> 4) + f) * 128 + (kc0 >> 5) + kbw) * 512 + lane * 8;
    }
    unsigned short* AsW = &As[wave * 2048];
    unsigned short* BsW = &Bs[(wave * 2) * 512];
    f32x4 acc[2][4] = {};
    GEMM_CORE_LOOP(KE, k0, (size_t)(k0 >> 5) * 512)
    #pragma unroll
    for (int mt = 0; mt < 2; ++mt) {
        #pragma unroll
        for (int reg = 0; reg < 4; ++reg) {
            int r = row0 + wave * 32 + mt * 16 + lq * 4 + reg;
            if (r < Mc) {
                int g = idxc[r];
                #pragma unroll
                for (int f = 0; f < 4; ++f)
                    atomicAdd(&Out[(size_t)g * D + d0 + f * 16 + ln], acc[mt][f][reg]);
            }
        }
    }
}

// ---------------------------------------------------------------------------
extern "C" void kernel_launch(void* const* d_in, const int* in_sizes, int n_in,
                              void* d_out, int out_size, void* d_ws,
                              size_t ws_size, hipStream_t stream) {
    const float* z    = (const float*)d_in[0];
    const int*   cid  = (const int*)d_in[1];
    const float* W1   = (const float*)d_in[2];
    const float* b1   = (const float*)d_in[3];
    const float* W2   = (const float*)d_in[4];
    const float* b2   = (const float*)d_in[5];
    const float* Wa   = (const float*)d_in[6];
    const float* ba   = (const float*)d_in[7];
    const float* Xbuf = (const float*)d_in[8];
    float* out = (float*)d_out;

    char* ws = (char*)d_ws;
    int*            cnt   = (int*)ws;                           // 256
    int*            idx   = (int*)(ws + 256);                   // 64 KB
    unsigned short* zbf   = (unsigned short*)(ws + 65792);      // 512 KB
    unsigned short* h     = (unsigned short*)(ws + 590080);     // 4 MB
    unsigned short* tbuf  = (unsigned short*)(ws + 4784384);    // 4 MB
    float*          L     = (float*)(ws + 8978688);             // 32 MB
    unsigned short* abuf  = (unsigned short*)(ws + 42533120);   // 16 MB
    unsigned short* Wf    = (unsigned short*)(ws + 59310336);   // 64 MB
    unsigned short* Xf    = (unsigned short*)(ws + 126419200);  // 32 MB
    unsigned short* W2f   = (unsigned short*)(ws + 159973632);  // 2 MB
    unsigned short* W1f   = (unsigned short*)(ws + 162070784);  // 256 KB

    hipMemsetAsync(cnt, 0, 256, stream);
    k_gather<<<dim3(B / 256), 256, 0, stream>>>(cid, cnt, idx);
    k_f2bf<<<dim3(256), 256, 0, stream>>>(z, zbf, B * LATENT / 4);
    k_repack_frag<<<dim3(4, 4, 1), 256, 0, stream>>>(W1, W1f, 128, HID, 0, 0, 0);
    k_repack_frag<<<dim3(32, 4, 1), 256, 0, stream>>>(W2, W2f, HID, HID, 0, 0, 0);
    k_repack_frag<<<dim3(32, 16, C), 256, 0, stream>>>(
        Wa, Wf, HID, NMAX, (size_t)HID * NMAX, 4194304, 1);
    k_repack_frag<<<dim3(128, 2, C), 256, 0, stream>>>(
        Xbuf, Xf, NMAX, D, (size_t)NMAX * D, 2097152, 2);
    k_mlp_mfma<<<dim3(B / 128, HID / 64), 256, 0, stream>>>(
        zbf, W1f, b1, W1 + (size_t)LATENT * HID, cid, h, LATENT);
    k_mlp_mfma<<<dim3(B / 128, HID / 64), 256, 0, stream>>>(
        h, W2f, b2, nullptr, cid, tbuf, HID);
    k_logits_mfma<<<dim3(B / 128, C, NMAX / 64), 256, 0, stream>>>(
        tbuf, Wf, ba, cnt, idx, L);
    k_softmax<<<dim3(B), 256, 0, stream>>>(L, abuf, cid);
    hipMemsetAsync(out, 0, (size_t)B * D * sizeof(float), stream);
    k_synth_mfma<<<dim3(B / 128, C, 32), 256, 0, stream>>>(
        abuf, Xf, cnt, idx, out);
}